// Round 8
// baseline (5549.180 us; speedup 1.0000x reference)
//
#include <hip/hip_runtime.h>
#include <hip/hip_fp16.h>

#define SEQ   2048
#define IND   256
#define NN    256

typedef _Float16 h2_t __attribute__((ext_vector_type(2)));

__device__ __forceinline__ float dot2f(unsigned a, unsigned b, float c) {
#if __has_builtin(__builtin_amdgcn_fdot2)
  union { unsigned u; h2_t h; } ua, ub;
  ua.u = a; ub.u = b;
  return __builtin_amdgcn_fdot2(ua.h, ub.h, c, false);
#else
  union { unsigned u; __half2 h; } ua, ub;
  ua.u = a; ub.u = b;
  return fmaf(__low2float(ua.h), __low2float(ub.h),
              fmaf(__high2float(ua.h), __high2float(ub.h), c));
#endif
}

__device__ __forceinline__ float fast_sigmoid(float x) {
  float e = __expf(-x);
  return __builtin_amdgcn_rcpf(1.f + e);
}
__device__ __forceinline__ float fast_tanh(float x) {
  x = fminf(15.f, fmaxf(-15.f, x));
  float e = __expf(2.f * x);
  return (e - 1.f) * __builtin_amdgcn_rcpf(e + 1.f);
}

// ---------------- K0: pack weights for the k-split scan (unchanged layout) -----
// Scan thread t (wave w=t>>6, lane l=t&63) owns:
//   gate cols j = l+64i (i<8), cand cols n = l+64i (i<4), k2-slice [16w,16w+16).
// slot = i*16+k (gate) or 128+i*16+k (cand).
// PK u32 idx = (slot>>2)*2048 + t*4 + (slot&3)  -> scan loads uint4, coalesced.
__global__ void pack_weights(const float* __restrict__ Wg,
                             const float* __restrict__ Wc,
                             unsigned* __restrict__ PK) {
  int idx = blockIdx.x * 256 + threadIdx.x;   // < 512*192 = 98304
  int s4  = idx >> 11;
  int rem = idx & 2047;
  int t   = rem >> 2;
  int slot = s4 * 4 + (rem & 3);
  int w = t >> 6, l = t & 63;
  float lo, hi;
  if (slot < 128) {
    int i = slot >> 4, k = slot & 15;
    int col = l + 64 * i;
    int k2 = 16 * w + k;
    lo = Wg[(256 + 2 * k2) * 512 + col];
    hi = Wg[(257 + 2 * k2) * 512 + col];
  } else {
    int s = slot - 128;
    int i = s >> 4, k = s & 15;
    int n = l + 64 * i;
    int k2 = 16 * w + k;
    lo = Wc[(256 + 2 * k2) * 256 + n];
    hi = Wc[(257 + 2 * k2) * 256 + n];
  }
  union { __half2 h; unsigned u; } cv;
  cv.h = __floats2half2_rn(lo, hi);
  PK[idx] = cv.u;
}

// ---------------- K1: x-projection GEMM (unchanged) ----------------------------
__global__ __launch_bounds__(256) void xproj_gemm(
    const float* __restrict__ x, const float* __restrict__ Wg,
    const float* __restrict__ Wc, __half* XG, __half* XC) {
  __shared__ float As[16][68];
  __shared__ float Bs[16][64];
  const int i0 = blockIdx.x * 64;
  const int j0 = blockIdx.y * 64;
  const int tid = threadIdx.x;
  const int tr = tid >> 4, tc = tid & 15;
  const int arow = tid >> 2, ac4 = (tid & 3) * 4;
  const int bk = tid >> 4, bj4 = (tid & 15) * 4;
  const bool isG = (j0 < 512);
  const float* B = isG ? Wg : Wc;
  const int ldb = isG ? 512 : 256;
  const int jb  = (isG ? j0 : (j0 - 512)) + bj4;
  float acc[4][4] = {};
  for (int k0 = 0; k0 < IND; k0 += 16) {
    float4 av = *(const float4*)&x[(size_t)(i0 + arow) * IND + k0 + ac4];
    As[ac4+0][arow] = av.x; As[ac4+1][arow] = av.y;
    As[ac4+2][arow] = av.z; As[ac4+3][arow] = av.w;
    *(float4*)&Bs[bk][bj4] = *(const float4*)&B[(size_t)(k0 + bk) * ldb + jb];
    __syncthreads();
#pragma unroll
    for (int k = 0; k < 16; ++k) {
      float4 a4 = *(const float4*)&As[k][tr * 4];
      float4 b4 = *(const float4*)&Bs[k][tc * 4];
      float a[4] = {a4.x, a4.y, a4.z, a4.w};
      float b[4] = {b4.x, b4.y, b4.z, b4.w};
#pragma unroll
      for (int r = 0; r < 4; ++r)
#pragma unroll
        for (int c = 0; c < 4; ++c) acc[r][c] = fmaf(a[r], b[c], acc[r][c]);
    }
    __syncthreads();
  }
  for (int r = 0; r < 4; ++r) {
    const size_t i = i0 + tr * 4 + r;
    const int j = j0 + tc * 4;
    __half2 p0 = __floats2half2_rn(acc[r][0], acc[r][1]);
    __half2 p1 = __floats2half2_rn(acc[r][2], acc[r][3]);
    union { __half2 h2[2]; uint2 u; } pk; pk.h2[0] = p0; pk.h2[1] = p1;
    if (isG) *(uint2*)&XG[i * 512 + j]         = pk.u;
    else     *(uint2*)&XC[i * 256 + (j - 512)] = pk.u;
  }
}

// ---------------- K2: AGPR-resident k-split GRU scan ---------------------------
// One block per batch, 512 threads = 8 waves. Wave w owns k2-slice [16w,16w+16).
// All 192 weight u32 pinned in AGPRs via explicit v_accvgpr_write/read (the
// compiler provably won't keep them in VGPRs: rounds 4/5 both landed at ~120
// VGPR and ~3600 cyc/step). ~60 VGPR + 192 AGPR = ~252 unified regs, 2 waves/EU.
__global__ __launch_bounds__(512, 2) void gru_scan(
    const unsigned* __restrict__ PK,
    const float* __restrict__ bg, const float* __restrict__ bc,
    const float* __restrict__ h0,
    const __half* __restrict__ XG, const __half* __restrict__ XC,
    float* __restrict__ out) {
  __shared__ unsigned h2s[128];      // h as 256 halves
  __shared__ unsigned rh2s[128];     // r*h as 256 halves
  __shared__ float pG[512 * 9];      // gate partials [col][wave], stride 9 (conflict-free)
  __shared__ float pC[256 * 9];      // cand partials
  __shared__ float uarr[256];
  const int b    = blockIdx.x;
  const int tid  = threadIdx.x;
  const int wave = tid >> 6, lane = tid & 63;

  // one-time: load 192 u32 of weights (coalesced uint4) and pin them in AGPRs
  unsigned wa[192];
  {
    const uint4* p = (const uint4*)PK + tid;
#pragma unroll
    for (int s4 = 0; s4 < 48; ++s4) {
      uint4 v = p[s4 * 512];
      asm volatile("v_accvgpr_write_b32 %0, %1" : "=a"(wa[4*s4+0]) : "v"(v.x));
      asm volatile("v_accvgpr_write_b32 %0, %1" : "=a"(wa[4*s4+1]) : "v"(v.y));
      asm volatile("v_accvgpr_write_b32 %0, %1" : "=a"(wa[4*s4+2]) : "v"(v.z));
      asm volatile("v_accvgpr_write_b32 %0, %1" : "=a"(wa[4*s4+3]) : "v"(v.w));
    }
  }

  const float bgj = bg[tid];
  const float bcn = (tid < 256) ? bc[tid] : 0.f;
  float hn = 0.f;
  if (tid < 256) {
    hn = h0[b * NN + tid];
    ((__half*)h2s)[tid] = __float2half_rn(hn);
  }
  __syncthreads();

  const size_t rowbase = (size_t)b * SEQ;
  for (int t = 0; t < SEQ; ++t) {
    const size_t row = rowbase + t;
    // prefetch x-projections (used after BAR1/BAR3; loads precede out-writes)
    const float xg = __half2float(XG[row * 512 + tid]);
    float xc = 0.f;
    if (tid < 256) xc = __half2float(XC[row * 256 + tid]);

    // ---- phase A: gate partials over this wave's k-slice ----
    unsigned hk[16];
    {
      const uint4* hb = (const uint4*)h2s + wave * 4;   // wave-uniform: broadcast
      ((uint4*)hk)[0] = hb[0]; ((uint4*)hk)[1] = hb[1];
      ((uint4*)hk)[2] = hb[2]; ((uint4*)hk)[3] = hb[3];
    }
#pragma unroll
    for (int i = 0; i < 8; ++i) {
      float pa = 0.f;
#pragma unroll
      for (int k = 0; k < 16; ++k) {
        unsigned wv;
        asm volatile("v_accvgpr_read_b32 %0, %1" : "=v"(wv) : "a"(wa[i*16+k]));
        pa = dot2f(wv, hk[k], pa);
      }
      pG[(lane + 64 * i) * 9 + wave] = pa;
    }
    __syncthreads();                                    // BAR1

    // ---- reduce A: thread j finalizes gate col j ----
    float s = bgj + xg;
#pragma unroll
    for (int w = 0; w < 8; ++w) s += pG[tid * 9 + w];
    const float g = fast_sigmoid(s);
    if (tid < 256) ((__half*)rh2s)[tid] = __float2half_rn(g * hn);
    else           uarr[tid - 256] = g;
    __syncthreads();                                    // BAR2

    // ---- phase B: cand partials over this wave's k-slice ----
    unsigned rk[16];
    {
      const uint4* rb = (const uint4*)rh2s + wave * 4;
      ((uint4*)rk)[0] = rb[0]; ((uint4*)rk)[1] = rb[1];
      ((uint4*)rk)[2] = rb[2]; ((uint4*)rk)[3] = rb[3];
    }
#pragma unroll
    for (int i = 0; i < 4; ++i) {
      float pc = 0.f;
#pragma unroll
      for (int k = 0; k < 16; ++k) {
        unsigned wv;
        asm volatile("v_accvgpr_read_b32 %0, %1" : "=v"(wv) : "a"(wa[128 + i*16 + k]));
        pc = dot2f(wv, rk[k], pc);
      }
      pC[(lane + 64 * i) * 9 + wave] = pc;
    }
    __syncthreads();                                    // BAR3

    // ---- reduce B: thread n finalizes state n ----
    if (tid < 256) {
      float sc = bcn + xc;
#pragma unroll
      for (int w = 0; w < 8; ++w) sc += pC[tid * 9 + w];
      const float c = fast_tanh(sc);
      const float u = uarr[tid];
      hn = u * hn + (1.f - u) * c;
      out[row * 256 + tid] = hn;      // overwrites XG row t (consumed pre-BAR1)
      ((__half*)h2s)[tid] = __float2half_rn(hn);
    }
    __syncthreads();                                    // BAR4
  }
}

extern "C" void kernel_launch(void* const* d_in, const int* in_sizes, int n_in,
                              void* d_out, int out_size, void* d_ws, size_t ws_size,
                              hipStream_t stream) {
  const float* x  = (const float*)d_in[0];
  const float* h0 = (const float*)d_in[1];
  const float* Wg = (const float*)d_in[2];
  const float* bg = (const float*)d_in[3];
  const float* Wc = (const float*)d_in[4];
  const float* bc = (const float*)d_in[5];

  char* ws = (char*)d_ws;
  __half*   XC = (__half*)ws;                     // 65536*256*2 = 33,554,432 B
  unsigned* PK = (unsigned*)(ws + 33554432);      // 512*192*4   =    393,216 B
  __half*   XG = (__half*)d_out;                  // 64 MB, reused as out
  float*    out = (float*)d_out;

  hipLaunchKernelGGL(pack_weights, dim3(384), dim3(256), 0, stream, Wg, Wc, PK);
  hipLaunchKernelGGL(xproj_gemm, dim3(1024, 12), dim3(256), 0, stream, x, Wg, Wc, XG, XC);
  hipLaunchKernelGGL(gru_scan, dim3(32), dim3(512), 0, stream,
                     PK, bg, bc, h0, XG, XC, out);
}

// Round 10
// 4497.917 us; speedup vs baseline: 1.2337x; 1.2337x over previous
//
#include <hip/hip_runtime.h>
#include <hip/hip_fp16.h>

#define SEQ   2048
#define IND   256
#define NN    256

typedef _Float16 h2_t __attribute__((ext_vector_type(2)));

__device__ __forceinline__ float dot2f(unsigned a, unsigned b, float c) {
#if __has_builtin(__builtin_amdgcn_fdot2)
  union { unsigned u; h2_t h; } ua, ub;
  ua.u = a; ub.u = b;
  return __builtin_amdgcn_fdot2(ua.h, ub.h, c, false);
#else
  union { unsigned u; __half2 h; } ua, ub;
  ua.u = a; ub.u = b;
  return fmaf(__low2float(ua.h), __low2float(ub.h),
              fmaf(__high2float(ua.h), __high2float(ub.h), c));
#endif
}

// Non-volatile AGPR read with a dummy loop-variant dependence: blocks LICM from
// hoisting reads out of the t-loop (which would spill), but leaves the
// scheduler free to interleave with dot2s (round 8's volatile pin cost +1.5ms).
__device__ __forceinline__ unsigned aread(const unsigned& a, int dep) {
  unsigned v;
  asm("v_accvgpr_read_b32 %0, %1" : "=v"(v) : "a"(a), "v"(dep));
  return v;
}

__device__ __forceinline__ float fast_sigmoid(float x) {
  float e = __expf(-x);
  return __builtin_amdgcn_rcpf(1.f + e);
}
__device__ __forceinline__ float fast_tanh(float x) {
  x = fminf(15.f, fmaxf(-15.f, x));
  float e = __expf(2.f * x);
  return (e - 1.f) * __builtin_amdgcn_rcpf(e + 1.f);
}

// ---------------- K0: pack weights for the k-split scan (unchanged layout) -----
// Scan thread t (wave w=t>>6, lane l=t&63) owns:
//   gate cols j = l+64i (i<8), cand cols n = l+64i (i<4), k2-slice [16w,16w+16).
// slot = i*16+k (gate) or 128+i*16+k (cand).
// PK u32 idx = (slot>>2)*2048 + t*4 + (slot&3)  -> scan loads uint4, coalesced.
__global__ void pack_weights(const float* __restrict__ Wg,
                             const float* __restrict__ Wc,
                             unsigned* __restrict__ PK) {
  int idx = blockIdx.x * 256 + threadIdx.x;   // < 512*192 = 98304
  int s4  = idx >> 11;
  int rem = idx & 2047;
  int t   = rem >> 2;
  int slot = s4 * 4 + (rem & 3);
  int w = t >> 6, l = t & 63;
  float lo, hi;
  if (slot < 128) {
    int i = slot >> 4, k = slot & 15;
    int col = l + 64 * i;
    int k2 = 16 * w + k;
    lo = Wg[(256 + 2 * k2) * 512 + col];
    hi = Wg[(257 + 2 * k2) * 512 + col];
  } else {
    int s = slot - 128;
    int i = s >> 4, k = s & 15;
    int n = l + 64 * i;
    int k2 = 16 * w + k;
    lo = Wc[(256 + 2 * k2) * 256 + n];
    hi = Wc[(257 + 2 * k2) * 256 + n];
  }
  union { __half2 h; unsigned u; } cv;
  cv.h = __floats2half2_rn(lo, hi);
  PK[idx] = cv.u;
}

// ---------------- K1: x-projection GEMM (unchanged) ----------------------------
__global__ __launch_bounds__(256) void xproj_gemm(
    const float* __restrict__ x, const float* __restrict__ Wg,
    const float* __restrict__ Wc, __half* XG, __half* XC) {
  __shared__ float As[16][68];
  __shared__ float Bs[16][64];
  const int i0 = blockIdx.x * 64;
  const int j0 = blockIdx.y * 64;
  const int tid = threadIdx.x;
  const int tr = tid >> 4, tc = tid & 15;
  const int arow = tid >> 2, ac4 = (tid & 3) * 4;
  const int bk = tid >> 4, bj4 = (tid & 15) * 4;
  const bool isG = (j0 < 512);
  const float* B = isG ? Wg : Wc;
  const int ldb = isG ? 512 : 256;
  const int jb  = (isG ? j0 : (j0 - 512)) + bj4;
  float acc[4][4] = {};
  for (int k0 = 0; k0 < IND; k0 += 16) {
    float4 av = *(const float4*)&x[(size_t)(i0 + arow) * IND + k0 + ac4];
    As[ac4+0][arow] = av.x; As[ac4+1][arow] = av.y;
    As[ac4+2][arow] = av.z; As[ac4+3][arow] = av.w;
    *(float4*)&Bs[bk][bj4] = *(const float4*)&B[(size_t)(k0 + bk) * ldb + jb];
    __syncthreads();
#pragma unroll
    for (int k = 0; k < 16; ++k) {
      float4 a4 = *(const float4*)&As[k][tr * 4];
      float4 b4 = *(const float4*)&Bs[k][tc * 4];
      float a[4] = {a4.x, a4.y, a4.z, a4.w};
      float b[4] = {b4.x, b4.y, b4.z, b4.w};
#pragma unroll
      for (int r = 0; r < 4; ++r)
#pragma unroll
        for (int c = 0; c < 4; ++c) acc[r][c] = fmaf(a[r], b[c], acc[r][c]);
    }
    __syncthreads();
  }
  for (int r = 0; r < 4; ++r) {
    const size_t i = i0 + tr * 4 + r;
    const int j = j0 + tc * 4;
    __half2 p0 = __floats2half2_rn(acc[r][0], acc[r][1]);
    __half2 p1 = __floats2half2_rn(acc[r][2], acc[r][3]);
    union { __half2 h2[2]; uint2 u; } pk; pk.h2[0] = p0; pk.h2[1] = p1;
    if (isG) *(uint2*)&XG[i * 512 + j]         = pk.u;
    else     *(uint2*)&XC[i * 256 + (j - 512)] = pk.u;
  }
}

// ---------------- K2: split-residency k-split GRU scan -------------------------
// One block per batch, 512 threads = 8 waves. Wave w owns k2-slice [16w,16w+16).
// Gate weights (128 u32) pinned in AGPRs, read via NON-volatile accvgpr_read
// with a t-dependence (schedulable, not hoistable). Cand weights (64 u32) left
// as a plain array -- the compiler keeps 64-element arrays VGPR-resident
// (round 1 evidence). ~120 arch VGPR + 128 AGPR < 256 unified @ 2 waves/EU.
__global__ __launch_bounds__(512, 2) void gru_scan(
    const unsigned* __restrict__ PK,
    const float* __restrict__ bg, const float* __restrict__ bc,
    const float* __restrict__ h0,
    const __half* __restrict__ XG, const __half* __restrict__ XC,
    float* __restrict__ out) {
  __shared__ unsigned h2s[128];      // h as 256 halves
  __shared__ unsigned rh2s[128];     // r*h as 256 halves
  __shared__ float pG[512 * 9];      // gate partials [col][wave], stride 9 (conflict-free)
  __shared__ float pC[256 * 9];      // cand partials
  __shared__ float uarr[256];
  const int b    = blockIdx.x;
  const int tid  = threadIdx.x;
  const int wave = tid >> 6, lane = tid & 63;

  // one-time: gate weights -> AGPRs (slots 0..127), cand weights -> VGPR array
  unsigned wag[128];
  unsigned wc[64];
  {
    const uint4* p = (const uint4*)PK + tid;
#pragma unroll
    for (int s4 = 0; s4 < 32; ++s4) {
      uint4 v = p[s4 * 512];
      asm("v_accvgpr_write_b32 %0, %1" : "=a"(wag[4*s4+0]) : "v"(v.x));
      asm("v_accvgpr_write_b32 %0, %1" : "=a"(wag[4*s4+1]) : "v"(v.y));
      asm("v_accvgpr_write_b32 %0, %1" : "=a"(wag[4*s4+2]) : "v"(v.z));
      asm("v_accvgpr_write_b32 %0, %1" : "=a"(wag[4*s4+3]) : "v"(v.w));
    }
#pragma unroll
    for (int s4 = 32; s4 < 48; ++s4) ((uint4*)wc)[s4 - 32] = p[s4 * 512];
  }

  const float bgj = bg[tid];
  const float bcn = (tid < 256) ? bc[tid] : 0.f;
  float hn = 0.f;
  if (tid < 256) {
    hn = h0[b * NN + tid];
    ((__half*)h2s)[tid] = __float2half_rn(hn);
  }
  __syncthreads();

  const size_t rowbase = (size_t)b * SEQ;
  for (int t = 0; t < SEQ; ++t) {
    const size_t row = rowbase + t;
    // prefetch x-projections (used after BAR1/BAR3; loads precede out-writes)
    const float xg = __half2float(XG[row * 512 + tid]);
    float xc = 0.f;
    if (tid < 256) xc = __half2float(XC[row * 256 + tid]);

    // ---- phase A: gate partials over this wave's k-slice (AGPR weights) ----
    unsigned hk[16];
    {
      const uint4* hb = (const uint4*)h2s + wave * 4;   // wave-uniform: broadcast
      ((uint4*)hk)[0] = hb[0]; ((uint4*)hk)[1] = hb[1];
      ((uint4*)hk)[2] = hb[2]; ((uint4*)hk)[3] = hb[3];
    }
#pragma unroll
    for (int i = 0; i < 8; ++i) {
      float pa = 0.f;
#pragma unroll
      for (int k = 0; k < 16; ++k)
        pa = dot2f(aread(wag[i * 16 + k], t), hk[k], pa);
      pG[(lane + 64 * i) * 9 + wave] = pa;
    }
    __syncthreads();                                    // BAR1

    // ---- reduce A: thread j finalizes gate col j ----
    float s = bgj + xg;
#pragma unroll
    for (int w = 0; w < 8; ++w) s += pG[tid * 9 + w];
    const float g = fast_sigmoid(s);
    if (tid < 256) ((__half*)rh2s)[tid] = __float2half_rn(g * hn);
    else           uarr[tid - 256] = g;
    __syncthreads();                                    // BAR2

    // ---- phase B: cand partials over this wave's k-slice (VGPR weights) ----
    unsigned rk[16];
    {
      const uint4* rb = (const uint4*)rh2s + wave * 4;
      ((uint4*)rk)[0] = rb[0]; ((uint4*)rk)[1] = rb[1];
      ((uint4*)rk)[2] = rb[2]; ((uint4*)rk)[3] = rb[3];
    }
#pragma unroll
    for (int i = 0; i < 4; ++i) {
      float pc = 0.f;
#pragma unroll
      for (int k = 0; k < 16; ++k) pc = dot2f(wc[i * 16 + k], rk[k], pc);
      pC[(lane + 64 * i) * 9 + wave] = pc;
    }
    __syncthreads();                                    // BAR3

    // ---- reduce B: thread n finalizes state n ----
    if (tid < 256) {
      float sc = bcn + xc;
#pragma unroll
      for (int w = 0; w < 8; ++w) sc += pC[tid * 9 + w];
      const float c = fast_tanh(sc);
      const float u = uarr[tid];
      hn = u * hn + (1.f - u) * c;
      out[row * 256 + tid] = hn;      // overwrites XG row t (consumed pre-BAR1)
      ((__half*)h2s)[tid] = __float2half_rn(hn);
    }
    __syncthreads();                                    // BAR4
  }
}

extern "C" void kernel_launch(void* const* d_in, const int* in_sizes, int n_in,
                              void* d_out, int out_size, void* d_ws, size_t ws_size,
                              hipStream_t stream) {
  const float* x  = (const float*)d_in[0];
  const float* h0 = (const float*)d_in[1];
  const float* Wg = (const float*)d_in[2];
  const float* bg = (const float*)d_in[3];
  const float* Wc = (const float*)d_in[4];
  const float* bc = (const float*)d_in[5];

  char* ws = (char*)d_ws;
  __half*   XC = (__half*)ws;                     // 65536*256*2 = 33,554,432 B
  unsigned* PK = (unsigned*)(ws + 33554432);      // 512*192*4   =    393,216 B
  __half*   XG = (__half*)d_out;                  // 64 MB, reused as out
  float*    out = (float*)d_out;

  hipLaunchKernelGGL(pack_weights, dim3(384), dim3(256), 0, stream, Wg, Wc, PK);
  hipLaunchKernelGGL(xproj_gemm, dim3(1024, 12), dim3(256), 0, stream, x, Wg, Wc, XG, XC);
  hipLaunchKernelGGL(gru_scan, dim3(32), dim3(512), 0, stream,
                     PK, bg, bc, h0, XG, XC, out);
}